// Round 1
// baseline (108.269 us; speedup 1.0000x reference)
//
#include <hip/hip_runtime.h>
#include <hip/hip_bf16.h>

#define BATCH 8192
#define NF 512
#define NL 1024
#define ATOMS 513

typedef float float4v __attribute__((ext_vector_type(4)));
typedef short short8 __attribute__((ext_vector_type(8)));

// fp32 -> bf16 bits, round-to-nearest-even
__device__ __forceinline__ unsigned short f2bf(float f) {
    union { float f; unsigned int u; } cv; cv.f = f;
    unsigned int u = cv.u;
    u += 0x7fffu + ((u >> 16) & 1u);
    return (unsigned short)(u >> 16);
}

// ---------------- Kernel 1: per-leaf softmax over 513 atoms ----------------
// Writes Wb[l][k] = bf16(softmax[l][k+1])  (k = 0..511, contiguous)
// and   bias[l]   = softmax[l][0]          (weight of the constant-1 atom)
__global__ void softmax_kernel(const float* __restrict__ logits,
                               unsigned short* __restrict__ Wb,
                               float* __restrict__ bias) {
    int l = blockIdx.x;
    int t = threadIdx.x;
    const float* row = logits + (size_t)l * ATOMS;
    float v0 = row[t];            // 0..255
    float v1 = row[t + 256];      // 256..511 (always valid, 511 < 513)
    float v2 = (t == 0) ? row[512] : -1e30f;

    __shared__ float red[256];
    float m = fmaxf(fmaxf(v0, v1), v2);
    red[t] = m; __syncthreads();
    for (int s = 128; s > 0; s >>= 1) {
        if (t < s) red[t] = fmaxf(red[t], red[t + s]);
        __syncthreads();
    }
    float mx = red[0];
    __syncthreads();

    float e0 = __expf(v0 - mx);
    float e1 = __expf(v1 - mx);
    float e2 = (t == 0) ? __expf(v2 - mx) : 0.f;
    red[t] = e0 + e1 + e2; __syncthreads();
    for (int s = 128; s > 0; s >>= 1) {
        if (t < s) red[t] += red[t + s];
        __syncthreads();
    }
    float inv = 1.f / red[0];

    unsigned short* wrow = Wb + (size_t)l * NF;
    if (t == 0) {
        bias[l] = e0 * inv;            // atom 0 (constant 1)
        wrow[511] = f2bf(e2 * inv);    // atom 512 -> k=511
    } else {
        wrow[t - 1] = f2bf(e0 * inv);  // atoms 1..255 -> k=0..254
    }
    wrow[t + 255] = f2bf(e1 * inv);    // atoms 256..511 -> k=255..510
}

// ---------------- Kernel 2: fused bf16-MFMA GEMM + logsumexp ----------------
// Block: 32 batch rows, 4 waves. Wave w: leaves [w*256, w*256+256).
// K = 512, 16 k-tiles of 32. mfma_f32_16x16x32_bf16:
//   A frag: A[m=lane&15][k = (lane>>4)*8 + j]  (8 bf16 / lane)
//   B frag: B[k = (lane>>4)*8 + j][n=lane&15]
//   C/D  : col = lane&15, row = (lane>>4)*4 + r
__global__ __launch_bounds__(256, 1)
void gemm_lse_kernel(const float* __restrict__ X,
                     const unsigned short* __restrict__ Wb,
                     const float* __restrict__ bias,
                     float* __restrict__ out) {
    int tid  = threadIdx.x;
    int wave = tid >> 6;
    int lane = tid & 63;
    int quad = lane >> 4;
    int l16  = lane & 15;
    int R0   = blockIdx.x * 32;
    int nBase = wave * 256;

    float4v acc[16][2];
#pragma unroll
    for (int nt = 0; nt < 16; ++nt)
#pragma unroll
        for (int mt = 0; mt < 2; ++mt)
            acc[nt][mt] = (float4v){0.f, 0.f, 0.f, 0.f};

    for (int kt = 0; kt < 16; ++kt) {
        int kb = kt * 32 + quad * 8;
        short8 afrag[2];
#pragma unroll
        for (int mt = 0; mt < 2; ++mt) {
            const float* xr = X + (size_t)(R0 + mt * 16 + l16) * NF + kb;
            float4v x0 = *reinterpret_cast<const float4v*>(xr);
            float4v x1 = *reinterpret_cast<const float4v*>(xr + 4);
            short8 a;
            a[0] = (short)f2bf(x0[0]); a[1] = (short)f2bf(x0[1]);
            a[2] = (short)f2bf(x0[2]); a[3] = (short)f2bf(x0[3]);
            a[4] = (short)f2bf(x1[0]); a[5] = (short)f2bf(x1[1]);
            a[6] = (short)f2bf(x1[2]); a[7] = (short)f2bf(x1[3]);
            afrag[mt] = a;
        }
#pragma unroll
        for (int nt = 0; nt < 16; ++nt) {
            int n = nBase + nt * 16 + l16;
            short8 b = *reinterpret_cast<const short8*>(
                reinterpret_cast<const short*>(Wb) + (size_t)n * NF + kb);
            acc[nt][0] = __builtin_amdgcn_mfma_f32_16x16x32_bf16(afrag[0], b, acc[nt][0], 0, 0, 0);
            acc[nt][1] = __builtin_amdgcn_mfma_f32_16x16x32_bf16(afrag[1], b, acc[nt][1], 0, 0, 0);
        }
    }

    // Epilogue: partial[mt][r] = sum over this wave's 256 leaves of exp(c + bias)
    float partial[2][4];
#pragma unroll
    for (int mt = 0; mt < 2; ++mt)
#pragma unroll
        for (int r = 0; r < 4; ++r) partial[mt][r] = 0.f;

#pragma unroll
    for (int nt = 0; nt < 16; ++nt) {
        float bl = bias[nBase + nt * 16 + l16];
#pragma unroll
        for (int mt = 0; mt < 2; ++mt)
#pragma unroll
            for (int r = 0; r < 4; ++r)
                partial[mt][r] += __expf(acc[nt][mt][r] + bl);
    }

    // reduce across the 16 columns (lanes sharing the same quad)
#pragma unroll
    for (int m = 1; m < 16; m <<= 1)
#pragma unroll
        for (int mt = 0; mt < 2; ++mt)
#pragma unroll
            for (int r = 0; r < 4; ++r)
                partial[mt][r] += __shfl_xor(partial[mt][r], m, 64);

    __shared__ float sums[4][32];
    if (l16 == 0) {
#pragma unroll
        for (int mt = 0; mt < 2; ++mt)
#pragma unroll
            for (int r = 0; r < 4; ++r)
                sums[wave][mt * 16 + quad * 4 + r] = partial[mt][r];
    }
    __syncthreads();
    if (tid < 32) {
        float s = sums[0][tid] + sums[1][tid] + sums[2][tid] + sums[3][tid];
        out[R0 + tid] = logf(s);
    }
}

extern "C" void kernel_launch(void* const* d_in, const int* in_sizes, int n_in,
                              void* d_out, int out_size, void* d_ws, size_t ws_size,
                              hipStream_t stream) {
    const float* X      = (const float*)d_in[0];   // (8192, 512) fp32
    const float* logits = (const float*)d_in[1];   // (1024, 513) fp32
    float* out = (float*)d_out;                    // (8192,) fp32

    unsigned short* Wb = (unsigned short*)d_ws;                       // 1024*512 bf16 = 1 MB
    float* bias = (float*)((char*)d_ws + (size_t)NL * NF * 2);        // 1024 fp32

    softmax_kernel<<<NL, 256, 0, stream>>>(logits, Wb, bias);
    gemm_lse_kernel<<<BATCH / 32, 256, 0, stream>>>(X, Wb, bias, out);
}